// Round 2
// baseline (265.323 us; speedup 1.0000x reference)
//
#include <hip/hip_runtime.h>
#include <math.h>

typedef _Float16 h8 __attribute__((ext_vector_type(8)));
typedef _Float16 h4 __attribute__((ext_vector_type(4)));
typedef float    f4 __attribute__((ext_vector_type(4)));

#define NHEADS 6
#define HDIM   32
#define NTOK   512
#define NTAB   43   // rel_idx = qsum - ksum + 21 in [0,42]
#define LOG2E  1.44269504088896340736f

__device__ inline int ds3(int x) {  // digit sum base-8, 3 digits
  return (x >> 6) + ((x >> 3) & 7) + (x & 7);
}

// ---------------- tiny MLP (43 rows x 3->12->12->12->6) -------------------------
__device__ inline void ln_relu12(const float* x, float* t, const float* g, const float* b) {
  float mu = 0.f;
#pragma unroll
  for (int j = 0; j < 12; j++) mu += x[j];
  mu *= (1.f / 12.f);
  float var = 0.f;
#pragma unroll
  for (int j = 0; j < 12; j++) { float d = x[j] - mu; var += d * d; }
  var *= (1.f / 12.f);
  float inv = rsqrtf(var + 1e-5f);
#pragma unroll
  for (int j = 0; j < 12; j++) {
    float y = (x[j] - mu) * inv * g[j] + b[j];
    t[j] = y > 0.f ? y : 0.f;
  }
}

__device__ inline void mm12(const float* t, float* x, const float* w, const float* c) {
#pragma unroll
  for (int j = 0; j < 12; j++) {
    float acc = c[j];
#pragma unroll
    for (int i = 0; i < 12; i++) acc += t[i] * w[i * 12 + j];
    x[j] = acc;
  }
}

// ---------------- fused flash attention, S^T formulation ------------------------
// Single kernel, no prepack round-trip. grid (384, 2): blockIdx.x = bh
// (fastest-varying) so the 2 q-blocks of one (b,h) differ by 384 = 0 mod 8
// -> same XCD, co-resident -> K/V f32 re-reads (x2 only) largely L2-resident.
// Each wave owns FOUR 16-query tiles (q4): halves K/V HBM re-reads vs q2 and
// amortizes every K/V fragment load over 4 q-tiles.
// __launch_bounds__(256,3): 3 blocks/CU (LDS 39.9KB x3 = 119KB), unified
// VGPR budget ~168 -> the staging registers held across the MFMA region do
// NOT spill (round-1 failure mode: (256,4) capped budget at 128 -> 187MB of
// scratch traffic, latency-bound at 132us).
// Per chunk: issue-early global loads, compute on LDS[cur], convert+write
// LDS[nb] late, ONE barrier. Pos-bias MLP recomputed per block (43 threads,
// hidden under chunk-0 stage). Compute core identical to the verified
// 2-kernel version: S^T = K.Q^T with bias as MFMA C-operand (log2 domain),
// max-free softmax, P via wave-private LDS (2 buffers, ti&1), O^T = V^T.P,
// LDS-transpose epilogue.
__global__ __launch_bounds__(256, 3)
void fused_attn_kernel(const float* __restrict__ q, const float* __restrict__ k,
                       const float* __restrict__ v,
                       const float* __restrict__ pw, const float* __restrict__ pb,
                       const float* __restrict__ g1, const float* __restrict__ b1,
                       const float* __restrict__ w1, const float* __restrict__ c1,
                       const float* __restrict__ g2, const float* __restrict__ b2,
                       const float* __restrict__ w2, const float* __restrict__ c2,
                       const float* __restrict__ g3, const float* __restrict__ b3,
                       const float* __restrict__ w3, const float* __restrict__ c3,
                       float* __restrict__ out)
{
  __shared__ __align__(16) char smem[4][2][2304];  // [wave][ti&1]: Pt then Os
  __shared__ f4 posw4r[NTAB];        // posw4r[b] = {p[b],p[b-1],p[b-2],p[b-3]}
  __shared__ float posb_s[NTAB * NHEADS];
  __shared__ __align__(16) _Float16 Ks[2][64 * 40]; // chunk rows, stride 40 halves
  __shared__ __align__(16) _Float16 Vt[2][32 * 72]; // V^T: [c][key], stride 72

  const int tid  = threadIdx.x;
  const int wave = tid >> 6;
  const int lane = tid & 63;
  const int quad = lane >> 4;
  const int l16  = lane & 15;
  const int bh   = blockIdx.x;
  const int h    = bh % NHEADS;
  const int qq   = blockIdx.y;                    // 0..1
  const float SC = 0.17677669529663687f * LOG2E;  // 32^-0.5 * log2(e)

  const long bhbase = (long)bh * NTOK * HDIM;
  const float4* kg = (const float4*)(k + bhbase);  // 4096 float4 per (b,h)
  const float4* vg = (const float4*)(v + bhbase);

  // ---- pos-bias MLP: rows 0..42 of the candidate table (log2 domain) ----
  if (tid < NTAB) {
    const float bh_ = -7.0f;
    const float bw_ = (float)(tid / 15) - 7.0f;
    const float bd_ = (float)(tid % 15) - 7.0f;
    float x[12], t[12];
#pragma unroll
    for (int j = 0; j < 12; j++)
      x[j] = bh_ * pw[j] + bw_ * pw[12 + j] + bd_ * pw[24 + j] + pb[j];
    ln_relu12(x, t, g1, b1); mm12(t, x, w1, c1);
    ln_relu12(x, t, g2, b2); mm12(t, x, w2, c2);
    ln_relu12(x, t, g3, b3);
#pragma unroll
    for (int hd = 0; hd < NHEADS; hd++) {
      float acc = c3[hd];
#pragma unroll
      for (int i = 0; i < 12; i++) acc += t[i] * w3[i * NHEADS + hd];
      posb_s[tid * NHEADS + hd] = acc * LOG2E;
    }
  }

  // ---- stage chunk 0 (K rows + V^T) ----
#pragma unroll
  for (int i = 0; i < 2; i++) {
    int f = i * 256 + tid, row = f >> 3, c4 = f & 7;
    float4 e = kg[f];
    h4 eh = { (_Float16)e.x, (_Float16)e.y, (_Float16)e.z, (_Float16)e.w };
    *(h4*)&Ks[0][row * 40 + c4 * 4] = eh;
    float4 w = vg[f];
    Vt[0][(c4 * 4 + 0) * 72 + row] = (_Float16)w.x;
    Vt[0][(c4 * 4 + 1) * 72 + row] = (_Float16)w.y;
    Vt[0][(c4 * 4 + 2) * 72 + row] = (_Float16)w.z;
    Vt[0][(c4 * 4 + 3) * 72 + row] = (_Float16)w.w;
  }
  __syncthreads();

  // reversed-window bias vectors for this head
  if (tid >= 3 && tid < NTAB) {
    f4 pv = { posb_s[tid * NHEADS + h],       posb_s[(tid - 1) * NHEADS + h],
              posb_s[(tid - 2) * NHEADS + h], posb_s[(tid - 3) * NHEADS + h] };
    posw4r[tid] = pv;
  }

  // ---- Q fragments straight from global f32 (pre-scaled, log2 domain) ----
  // q-tiles: qq*16 + wave*4 + {0,1,2,3}   (tiles 0..31 per (b,h))
  int qt[4];
  h8 qf[4];
  int qs21[4];
#pragma unroll
  for (int ti = 0; ti < 4; ti++) {
    qt[ti] = qq * 16 + wave * 4 + ti;
    const float* qrow = q + bhbase + (long)(qt[ti] * 16 + l16) * HDIM + quad * 8;
    float4 a = *(const float4*)qrow;
    float4 b = *(const float4*)(qrow + 4);
    h8 qh = { (_Float16)(a.x * SC), (_Float16)(a.y * SC),
              (_Float16)(a.z * SC), (_Float16)(a.w * SC),
              (_Float16)(b.x * SC), (_Float16)(b.y * SC),
              (_Float16)(b.z * SC), (_Float16)(b.w * SC) };
    qf[ti] = qh;
    qs21[ti] = ds3(qt[ti] * 16) + (l16 >> 3) + (l16 & 7) + 21;
  }
  const int kdq = (quad >> 1) + (quad & 1) * 4;  // quad part of key digit-sum

  f4 o[4][2];
#pragma unroll
  for (int ti = 0; ti < 4; ti++) { o[ti][0] = f4{0,0,0,0}; o[ti][1] = f4{0,0,0,0}; }
  float lp[4] = {0.f, 0.f, 0.f, 0.f};

  __syncthreads();   // posw4r ready

#pragma unroll 2
  for (int kc = 0; kc < 8; kc++) {
    const int cur = kc & 1;

    // ---- issue next-chunk loads early (consumed after compute) ----
    float4 kreg0, kreg1, vreg0, vreg1;
    if (kc < 7) {
      const int fb = (kc + 1) * 512 + tid;
      kreg0 = kg[fb];       kreg1 = kg[fb + 256];
      vreg0 = vg[fb];       vreg1 = vg[fb + 256];
    }

    // ---- fragment loads from LDS, shared by all 4 q-tiles ----
    h8 kf[4], vf[4];
#pragma unroll
    for (int t = 0; t < 4; t++) {
      kf[t] = *(const h8*)&Ks[cur][(t * 16 + l16) * 40 + quad * 8];
      vf[t] = *(const h8*)&Vt[cur][((t & 1) * 16 + l16) * 72 + (t >> 1) * 32 + quad * 8];
    }

#pragma unroll
    for (int ti = 0; ti < 4; ti++) {
      _Float16* pt = (_Float16*)smem[wave][ti & 1];
      // ---- S^T = K.Q^T + bias (C operand; log2 domain) ----
      f4 s[4];
#pragma unroll
      for (int t = 0; t < 4; t++) {
        int idx0 = qs21[ti] - (kc + t * 2 + kdq);   // in [3,42]
        f4 cin = posw4r[idx0];                      // cin[r] = p[idx0-r]
        s[t] = __builtin_amdgcn_mfma_f32_16x16x32_f16(kf[t], qf[ti], cin, 0, 0, 0);
      }
      // ---- max-free softmax: p = 2^s; key-contiguous b64 P-writes ----
#pragma unroll
      for (int t = 0; t < 4; t++) {
        float p0 = __builtin_amdgcn_exp2f(s[t][0]);
        float p1 = __builtin_amdgcn_exp2f(s[t][1]);
        float p2 = __builtin_amdgcn_exp2f(s[t][2]);
        float p3 = __builtin_amdgcn_exp2f(s[t][3]);
        lp[ti] += (p0 + p1) + (p2 + p3);
        h4 hv = { (_Float16)p0, (_Float16)p1, (_Float16)p2, (_Float16)p3 };
        *(h4*)&pt[l16 * 72 + t * 16 + quad * 4] = hv;   // Pt[q][key]
      }
      // ---- O^T += V^T.P : B-frag = Pt[q=l16][keys quad*8..+7] (b128) ----
#pragma unroll
      for (int kt = 0; kt < 2; kt++) {
        h8 pf = *(const h8*)&pt[l16 * 72 + kt * 32 + quad * 8];
        o[ti][0] = __builtin_amdgcn_mfma_f32_16x16x32_f16(vf[kt * 2 + 0], pf, o[ti][0], 0, 0, 0);
        o[ti][1] = __builtin_amdgcn_mfma_f32_16x16x32_f16(vf[kt * 2 + 1], pf, o[ti][1], 0, 0, 0);
      }
    }

    // ---- write next chunk to the other LDS buffer, then one barrier ----
    if (kc < 7) {
      const int nb = cur ^ 1;
#pragma unroll
      for (int i = 0; i < 2; i++) {
        float4 e = (i == 0) ? kreg0 : kreg1;
        float4 w = (i == 0) ? vreg0 : vreg1;
        int f = i * 256 + tid, row = f >> 3, c4 = f & 7;
        h4 eh = { (_Float16)e.x, (_Float16)e.y, (_Float16)e.z, (_Float16)e.w };
        *(h4*)&Ks[nb][row * 40 + c4 * 4] = eh;
        Vt[nb][(c4 * 4 + 0) * 72 + row] = (_Float16)w.x;
        Vt[nb][(c4 * 4 + 1) * 72 + row] = (_Float16)w.y;
        Vt[nb][(c4 * 4 + 2) * 72 + row] = (_Float16)w.z;
        Vt[nb][(c4 * 4 + 3) * 72 + row] = (_Float16)w.w;
      }
      __syncthreads();
    }
  }

  // ---- epilogue: reduce l across quads, normalize, LDS transpose, store ----
#pragma unroll
  for (int ti = 0; ti < 4; ti++) {
    float l = lp[ti];
    l += __shfl_xor(l, 16);
    l += __shfl_xor(l, 32);
    const float inv = 1.f / l;      // full row sum for query col l16
    float* os = (float*)smem[wave][ti & 1];  // reuse Pt storage (same wave; in-order DS)
    f4 w0 = { o[ti][0][0] * inv, o[ti][0][1] * inv, o[ti][0][2] * inv, o[ti][0][3] * inv };
    f4 w1 = { o[ti][1][0] * inv, o[ti][1][1] * inv, o[ti][1][2] * inv, o[ti][1][3] * inv };
    *(f4*)&os[l16 * 36 + quad * 4]      = w0;   // Os[q][c], c = quad*4..+3
    *(f4*)&os[l16 * 36 + 16 + quad * 4] = w1;   // c = 16+quad*4..+3
    const int q_ = lane >> 2, seg = lane & 3;
    f4 r0 = *(const f4*)&os[q_ * 36 + seg * 8];
    f4 r1 = *(const f4*)&os[q_ * 36 + seg * 8 + 4];
    float* orow = out + (long)bh * NTOK * HDIM + (long)(qt[ti] * 16 + q_) * HDIM + seg * 8;
    *(float4*)orow       = *(float4*)&r0;   // fully coalesced 2 KB/wave
    *(float4*)(orow + 4) = *(float4*)&r1;
  }
}

extern "C" void kernel_launch(void* const* d_in, const int* in_sizes, int n_in,
                              void* d_out, int out_size, void* d_ws, size_t ws_size,
                              hipStream_t stream) {
  (void)in_sizes; (void)n_in; (void)out_size; (void)d_ws; (void)ws_size;
  const float* q  = (const float*)d_in[0];
  const float* k  = (const float*)d_in[1];
  const float* v  = (const float*)d_in[2];
  // d_in[3..5] = h,w,d scalars (always 8; hard-coded)
  const float* pw  = (const float*)d_in[6];
  const float* pb  = (const float*)d_in[7];
  const float* g1  = (const float*)d_in[8];
  const float* b1  = (const float*)d_in[9];
  const float* w1  = (const float*)d_in[10];
  const float* c1  = (const float*)d_in[11];
  const float* g2  = (const float*)d_in[12];
  const float* b2  = (const float*)d_in[13];
  const float* w2  = (const float*)d_in[14];
  const float* c2  = (const float*)d_in[15];
  const float* g3  = (const float*)d_in[16];
  const float* b3  = (const float*)d_in[17];
  const float* w3  = (const float*)d_in[18];
  const float* c3  = (const float*)d_in[19];
  float* outp = (float*)d_out;

  fused_attn_kernel<<<dim3(384, 2), 256, 0, stream>>>(
      q, k, v,
      pw, pb, g1, b1, w1, c1, g2, b2, w2, c2, g3, b3, w3, c3, outp);
}

// Round 3
// 172.912 us; speedup vs baseline: 1.5344x; 1.5344x over previous
//
#include <hip/hip_runtime.h>
#include <math.h>

typedef _Float16 h8 __attribute__((ext_vector_type(8)));
typedef _Float16 h4 __attribute__((ext_vector_type(4)));
typedef float    f4 __attribute__((ext_vector_type(4)));

#define NHEADS 6
#define HDIM   32
#define NTOK   512
#define NTAB   43   // rel_idx = qsum - ksum + 21 in [0,42]
#define LOG2E  1.44269504088896340736f

__device__ inline int ds3(int x) {  // digit sum base-8, 3 digits
  return (x >> 6) + ((x >> 3) & 7) + (x & 7);
}

// ---------------- tiny MLP (43 rows x 3->12->12->12->6) -------------------------
__device__ inline void ln_relu12(const float* x, float* t, const float* g, const float* b) {
  float mu = 0.f;
#pragma unroll
  for (int j = 0; j < 12; j++) mu += x[j];
  mu *= (1.f / 12.f);
  float var = 0.f;
#pragma unroll
  for (int j = 0; j < 12; j++) { float d = x[j] - mu; var += d * d; }
  var *= (1.f / 12.f);
  float inv = rsqrtf(var + 1e-5f);
#pragma unroll
  for (int j = 0; j < 12; j++) {
    float y = (x[j] - mu) * inv * g[j] + b[j];
    t[j] = y > 0.f ? y : 0.f;
  }
}

__device__ inline void mm12(const float* t, float* x, const float* w, const float* c) {
#pragma unroll
  for (int j = 0; j < 12; j++) {
    float acc = c[j];
#pragma unroll
    for (int i = 0; i < 12; i++) acc += t[i] * w[i * 12 + j];
    x[j] = acc;
  }
}

// ---------------- fused flash attention, S^T formulation ------------------------
// Single kernel, no prepack round-trip. grid (384, 4): blockIdx.x = bh
// (fastest-varying) so the 4 q-blocks of one (b,h) differ by 384 = 0 mod 8
// -> same XCD, co-resident -> K/V f32 re-reads largely L2-resident.
// Each wave owns TWO 16-query tiles.
//
// REGISTER DISCIPLINE (rounds 1-2 post-mortem): NO occupancy request in
// __launch_bounds__. With MFMA present the allocator splits the unified
// VGPR file into arch+acc halves, so (256,4)/(256,3) capped arch VGPRs at
// 64/84 while the k-loop holds ~110 live values -> 187-276 MB of scratch
// spill traffic per dispatch (WRITE_SIZE 212/301 MB vs 25 MB output),
// latency-bound at 132/150 us. Spill-freedom > occupancy here: grid is
// 1536 blocks = 6/CU, fills dominate the harness floor anyway.
//
// Per chunk: issue-early global loads, compute on LDS[cur], convert+write
// LDS[nb] late, ONE barrier. Pos-bias MLP recomputed per block (43 threads,
// hidden under chunk-0 stage). Compute core identical to the verified
// 2-kernel version: S^T = K.Q^T with bias as MFMA C-operand (log2 domain),
// max-free softmax, P via wave-private LDS, O^T = V^T.P, LDS-transpose
// epilogue.
__global__ __launch_bounds__(256)
void fused_attn_kernel(const float* __restrict__ q, const float* __restrict__ k,
                       const float* __restrict__ v,
                       const float* __restrict__ pw, const float* __restrict__ pb,
                       const float* __restrict__ g1, const float* __restrict__ b1,
                       const float* __restrict__ w1, const float* __restrict__ c1,
                       const float* __restrict__ g2, const float* __restrict__ b2,
                       const float* __restrict__ w2, const float* __restrict__ c2,
                       const float* __restrict__ g3, const float* __restrict__ b3,
                       const float* __restrict__ w3, const float* __restrict__ c3,
                       float* __restrict__ out)
{
  __shared__ __align__(16) char smem[4][2][2304];  // [wave][tile]: Pt then Os
  __shared__ f4 posw4r[NTAB];        // posw4r[b] = {p[b],p[b-1],p[b-2],p[b-3]}
  __shared__ float posb_s[NTAB * NHEADS];
  __shared__ __align__(16) _Float16 Ks[2][64 * 40]; // chunk rows, stride 40 halves
  __shared__ __align__(16) _Float16 Vt[2][32 * 72]; // V^T: [c][key], stride 72

  const int tid  = threadIdx.x;
  const int wave = tid >> 6;
  const int lane = tid & 63;
  const int quad = lane >> 4;
  const int l16  = lane & 15;
  const int bh   = blockIdx.x;
  const int h    = bh % NHEADS;
  const int qq   = blockIdx.y;                    // 0..3
  const float SC = 0.17677669529663687f * LOG2E;  // 32^-0.5 * log2(e)

  const long bhbase = (long)bh * NTOK * HDIM;
  const float4* kg = (const float4*)(k + bhbase);  // 4096 float4 per (b,h)
  const float4* vg = (const float4*)(v + bhbase);

  // ---- pos-bias MLP: rows 0..42 of the candidate table (log2 domain) ----
  if (tid < NTAB) {
    const float bh_ = -7.0f;
    const float bw_ = (float)(tid / 15) - 7.0f;
    const float bd_ = (float)(tid % 15) - 7.0f;
    float x[12], t[12];
#pragma unroll
    for (int j = 0; j < 12; j++)
      x[j] = bh_ * pw[j] + bw_ * pw[12 + j] + bd_ * pw[24 + j] + pb[j];
    ln_relu12(x, t, g1, b1); mm12(t, x, w1, c1);
    ln_relu12(x, t, g2, b2); mm12(t, x, w2, c2);
    ln_relu12(x, t, g3, b3);
#pragma unroll
    for (int hd = 0; hd < NHEADS; hd++) {
      float acc = c3[hd];
#pragma unroll
      for (int i = 0; i < 12; i++) acc += t[i] * w3[i * NHEADS + hd];
      posb_s[tid * NHEADS + hd] = acc * LOG2E;
    }
  }

  // ---- stage chunk 0 (K rows + V^T) ----
#pragma unroll
  for (int i = 0; i < 2; i++) {
    int f = i * 256 + tid, row = f >> 3, c4 = f & 7;
    float4 e = kg[f];
    h4 eh = { (_Float16)e.x, (_Float16)e.y, (_Float16)e.z, (_Float16)e.w };
    *(h4*)&Ks[0][row * 40 + c4 * 4] = eh;
    float4 w = vg[f];
    Vt[0][(c4 * 4 + 0) * 72 + row] = (_Float16)w.x;
    Vt[0][(c4 * 4 + 1) * 72 + row] = (_Float16)w.y;
    Vt[0][(c4 * 4 + 2) * 72 + row] = (_Float16)w.z;
    Vt[0][(c4 * 4 + 3) * 72 + row] = (_Float16)w.w;
  }
  __syncthreads();

  // reversed-window bias vectors for this head
  if (tid >= 3 && tid < NTAB) {
    f4 pv = { posb_s[tid * NHEADS + h],       posb_s[(tid - 1) * NHEADS + h],
              posb_s[(tid - 2) * NHEADS + h], posb_s[(tid - 3) * NHEADS + h] };
    posw4r[tid] = pv;
  }

  // ---- Q fragments straight from global f32 (pre-scaled, log2 domain) ----
  // q-tiles: qq*8 + wave*2 + {0,1}  (tiles 0..31 per (b,h))
  int qt[2] = { qq * 8 + wave * 2, qq * 8 + wave * 2 + 1 };
  h8 qf[2];
  int qs21[2];
#pragma unroll
  for (int ti = 0; ti < 2; ti++) {
    const float* qrow = q + bhbase + (long)(qt[ti] * 16 + l16) * HDIM + quad * 8;
    float4 a = *(const float4*)qrow;
    float4 b = *(const float4*)(qrow + 4);
    h8 qh = { (_Float16)(a.x * SC), (_Float16)(a.y * SC),
              (_Float16)(a.z * SC), (_Float16)(a.w * SC),
              (_Float16)(b.x * SC), (_Float16)(b.y * SC),
              (_Float16)(b.z * SC), (_Float16)(b.w * SC) };
    qf[ti] = qh;
    qs21[ti] = ds3(qt[ti] * 16) + (l16 >> 3) + (l16 & 7) + 21;
  }
  const int kdq = (quad >> 1) + (quad & 1) * 4;  // quad part of key digit-sum

  f4 o[2][2];
#pragma unroll
  for (int ti = 0; ti < 2; ti++) { o[ti][0] = f4{0,0,0,0}; o[ti][1] = f4{0,0,0,0}; }
  float lp[2] = {0.f, 0.f};

  __syncthreads();   // posw4r ready

#pragma unroll 2
  for (int kc = 0; kc < 8; kc++) {
    const int cur = kc & 1;

    // ---- issue next-chunk loads early (consumed after compute) ----
    float4 kreg0, kreg1, vreg0, vreg1;
    if (kc < 7) {
      const int fb = (kc + 1) * 512 + tid;
      kreg0 = kg[fb];       kreg1 = kg[fb + 256];
      vreg0 = vg[fb];       vreg1 = vg[fb + 256];
    }

    // ---- fragment loads from LDS, shared by both q-tiles ----
    h8 kf[4], vf[4];
#pragma unroll
    for (int t = 0; t < 4; t++) {
      kf[t] = *(const h8*)&Ks[cur][(t * 16 + l16) * 40 + quad * 8];
      vf[t] = *(const h8*)&Vt[cur][((t & 1) * 16 + l16) * 72 + (t >> 1) * 32 + quad * 8];
    }

#pragma unroll
    for (int ti = 0; ti < 2; ti++) {
      _Float16* pt = (_Float16*)smem[wave][ti];
      // ---- S^T = K.Q^T + bias (C operand; log2 domain) ----
      f4 s[4];
#pragma unroll
      for (int t = 0; t < 4; t++) {
        int idx0 = qs21[ti] - (kc + t * 2 + kdq);   // in [3,42]
        f4 cin = posw4r[idx0];                      // cin[r] = p[idx0-r]
        s[t] = __builtin_amdgcn_mfma_f32_16x16x32_f16(kf[t], qf[ti], cin, 0, 0, 0);
      }
      // ---- max-free softmax: p = 2^s; key-contiguous b64 P-writes ----
#pragma unroll
      for (int t = 0; t < 4; t++) {
        float p0 = __builtin_amdgcn_exp2f(s[t][0]);
        float p1 = __builtin_amdgcn_exp2f(s[t][1]);
        float p2 = __builtin_amdgcn_exp2f(s[t][2]);
        float p3 = __builtin_amdgcn_exp2f(s[t][3]);
        lp[ti] += (p0 + p1) + (p2 + p3);
        h4 hv = { (_Float16)p0, (_Float16)p1, (_Float16)p2, (_Float16)p3 };
        *(h4*)&pt[l16 * 72 + t * 16 + quad * 4] = hv;   // Pt[q][key]
      }
      // ---- O^T += V^T.P : B-frag = Pt[q=l16][keys quad*8..+7] (b128) ----
#pragma unroll
      for (int kt = 0; kt < 2; kt++) {
        h8 pf = *(const h8*)&pt[l16 * 72 + kt * 32 + quad * 8];
        o[ti][0] = __builtin_amdgcn_mfma_f32_16x16x32_f16(vf[kt * 2 + 0], pf, o[ti][0], 0, 0, 0);
        o[ti][1] = __builtin_amdgcn_mfma_f32_16x16x32_f16(vf[kt * 2 + 1], pf, o[ti][1], 0, 0, 0);
      }
    }

    // ---- write next chunk to the other LDS buffer, then one barrier ----
    if (kc < 7) {
      const int nb = cur ^ 1;
#pragma unroll
      for (int i = 0; i < 2; i++) {
        float4 e = (i == 0) ? kreg0 : kreg1;
        float4 w = (i == 0) ? vreg0 : vreg1;
        int f = i * 256 + tid, row = f >> 3, c4 = f & 7;
        h4 eh = { (_Float16)e.x, (_Float16)e.y, (_Float16)e.z, (_Float16)e.w };
        *(h4*)&Ks[nb][row * 40 + c4 * 4] = eh;
        Vt[nb][(c4 * 4 + 0) * 72 + row] = (_Float16)w.x;
        Vt[nb][(c4 * 4 + 1) * 72 + row] = (_Float16)w.y;
        Vt[nb][(c4 * 4 + 2) * 72 + row] = (_Float16)w.z;
        Vt[nb][(c4 * 4 + 3) * 72 + row] = (_Float16)w.w;
      }
      __syncthreads();
    }
  }

  // ---- epilogue: reduce l across quads, normalize, LDS transpose, store ----
#pragma unroll
  for (int ti = 0; ti < 2; ti++) {
    float l = lp[ti];
    l += __shfl_xor(l, 16);
    l += __shfl_xor(l, 32);
    const float inv = 1.f / l;      // full row sum for query col l16
    float* os = (float*)smem[wave][ti];   // reuse Pt storage (same wave; in-order DS)
    f4 w0 = { o[ti][0][0] * inv, o[ti][0][1] * inv, o[ti][0][2] * inv, o[ti][0][3] * inv };
    f4 w1 = { o[ti][1][0] * inv, o[ti][1][1] * inv, o[ti][1][2] * inv, o[ti][1][3] * inv };
    *(f4*)&os[l16 * 36 + quad * 4]      = w0;   // Os[q][c], c = quad*4..+3
    *(f4*)&os[l16 * 36 + 16 + quad * 4] = w1;   // c = 16+quad*4..+3
    const int q_ = lane >> 2, seg = lane & 3;
    f4 r0 = *(const f4*)&os[q_ * 36 + seg * 8];
    f4 r1 = *(const f4*)&os[q_ * 36 + seg * 8 + 4];
    float* orow = out + (long)bh * NTOK * HDIM + (long)(qt[ti] * 16 + q_) * HDIM + seg * 8;
    *(float4*)orow       = *(float4*)&r0;   // fully coalesced 2 KB/wave
    *(float4*)(orow + 4) = *(float4*)&r1;
  }
}

extern "C" void kernel_launch(void* const* d_in, const int* in_sizes, int n_in,
                              void* d_out, int out_size, void* d_ws, size_t ws_size,
                              hipStream_t stream) {
  (void)in_sizes; (void)n_in; (void)out_size; (void)d_ws; (void)ws_size;
  const float* q  = (const float*)d_in[0];
  const float* k  = (const float*)d_in[1];
  const float* v  = (const float*)d_in[2];
  // d_in[3..5] = h,w,d scalars (always 8; hard-coded)
  const float* pw  = (const float*)d_in[6];
  const float* pb  = (const float*)d_in[7];
  const float* g1  = (const float*)d_in[8];
  const float* b1  = (const float*)d_in[9];
  const float* w1  = (const float*)d_in[10];
  const float* c1  = (const float*)d_in[11];
  const float* g2  = (const float*)d_in[12];
  const float* b2  = (const float*)d_in[13];
  const float* w2  = (const float*)d_in[14];
  const float* c2  = (const float*)d_in[15];
  const float* g3  = (const float*)d_in[16];
  const float* b3  = (const float*)d_in[17];
  const float* w3  = (const float*)d_in[18];
  const float* c3  = (const float*)d_in[19];
  float* outp = (float*)d_out;

  fused_attn_kernel<<<dim3(384, 4), 256, 0, stream>>>(
      q, k, v,
      pw, pb, g1, b1, w1, c1, g2, b2, w2, c2, g3, b3, w3, c3, outp);
}

// Round 4
// 172.119 us; speedup vs baseline: 1.5415x; 1.0046x over previous
//
#include <hip/hip_runtime.h>
#include <math.h>

typedef _Float16 h8 __attribute__((ext_vector_type(8)));
typedef _Float16 h4 __attribute__((ext_vector_type(4)));
typedef float    f4 __attribute__((ext_vector_type(4)));

#define NHEADS 6
#define HDIM   32
#define NTOK   512
#define NTAB   43   // rel_idx = qsum - ksum + 21 in [0,42]
#define LOG2E  1.44269504088896340736f

__device__ inline int ds3(int x) {  // digit sum base-8, 3 digits
  return (x >> 6) + ((x >> 3) & 7) + (x & 7);
}

// ---------------- tiny MLP (43 rows x 3->12->12->12->6) -------------------------
__device__ inline void ln_relu12(const float* x, float* t, const float* g, const float* b) {
  float mu = 0.f;
#pragma unroll
  for (int j = 0; j < 12; j++) mu += x[j];
  mu *= (1.f / 12.f);
  float var = 0.f;
#pragma unroll
  for (int j = 0; j < 12; j++) { float d = x[j] - mu; var += d * d; }
  var *= (1.f / 12.f);
  float inv = rsqrtf(var + 1e-5f);
#pragma unroll
  for (int j = 0; j < 12; j++) {
    float y = (x[j] - mu) * inv * g[j] + b[j];
    t[j] = y > 0.f ? y : 0.f;
  }
}

__device__ inline void mm12(const float* t, float* x, const float* w, const float* c) {
#pragma unroll
  for (int j = 0; j < 12; j++) {
    float acc = c[j];
#pragma unroll
    for (int i = 0; i < 12; i++) acc += t[i] * w[i * 12 + j];
    x[j] = acc;
  }
}

// ---------------- fused flash attention, S^T formulation ------------------------
// Single kernel, no prepack round-trip. grid (384, 4): blockIdx.x = bh
// (fastest-varying) so the 4 q-blocks of one (b,h) differ by 384 = 0 mod 8
// -> same XCD, co-resident -> K/V f32 re-reads largely L2/L3-resident
// (round-3 FETCH 86 MB ~= unique inputs, confirmed).
//
// REGISTER DISCIPLINE (rounds 1-2 post-mortem): NO min-waves request in
// __launch_bounds__. With MFMA the allocator splits the unified VGPR file;
// (256,4)/(256,3) capped arch VGPRs at 64/84 < ~110 live -> 187-276 MB of
// scratch traffic. Spill-freedom > occupancy here.
//
// ROUND-4 CHANGE (round-3 post-mortem: latency-bound, nothing saturated,
// 6.79M LDS bank-conflict cycles, P round-trip serializes each q-tile):
// PV now uses v_mfma_f32_16x16x16f16 over 4 key-blocks of 16. Its B-frag
// layout B[k=quad*4+j][col=l16] IS the QK^T C-layout (row=quad*4+r,
// col=l16), so P = cvt(exp2(S^T)) feeds PV straight from registers -- the
// Pt LDS write/read round-trip (8 b64 w + 4 b128 r per wave-chunk, ~4-way
// conflicted, 2 lgkm serialization points) is deleted. V^T A-frags
// (A[row=c'][k=quad*4+j]) come from the same Vt[c][key] LDS layout as 8
// near-conflict-free b64 reads. D-layout (col=q, row=quad*4+r) is identical
// to the old 16x16x32 PV, so accumulators and epilogue are unchanged.
//
// Per chunk: issue-early global loads, compute on LDS[cur], convert+write
// LDS[nb] late, ONE barrier. Pos-bias MLP recomputed per block (43 threads,
// hidden under chunk-0 stage). S^T = K.Q^T with bias as MFMA C-operand
// (log2 domain), max-free softmax, LDS-transpose epilogue.
__global__ __launch_bounds__(256)
void fused_attn_kernel(const float* __restrict__ q, const float* __restrict__ k,
                       const float* __restrict__ v,
                       const float* __restrict__ pw, const float* __restrict__ pb,
                       const float* __restrict__ g1, const float* __restrict__ b1,
                       const float* __restrict__ w1, const float* __restrict__ c1,
                       const float* __restrict__ g2, const float* __restrict__ b2,
                       const float* __restrict__ w2, const float* __restrict__ c2,
                       const float* __restrict__ g3, const float* __restrict__ b3,
                       const float* __restrict__ w3, const float* __restrict__ c3,
                       float* __restrict__ out)
{
  __shared__ __align__(16) char smem[4][2][2304];  // [wave][tile]: epilogue Os
  __shared__ f4 posw4r[NTAB];        // posw4r[b] = {p[b],p[b-1],p[b-2],p[b-3]}
  __shared__ float posb_s[NTAB * NHEADS];
  __shared__ __align__(16) _Float16 Ks[2][64 * 40]; // chunk rows, stride 40 halves
  __shared__ __align__(16) _Float16 Vt[2][32 * 72]; // V^T: [c][key], stride 72

  const int tid  = threadIdx.x;
  const int wave = tid >> 6;
  const int lane = tid & 63;
  const int quad = lane >> 4;
  const int l16  = lane & 15;
  const int bh   = blockIdx.x;
  const int h    = bh % NHEADS;
  const int qq   = blockIdx.y;                    // 0..3
  const float SC = 0.17677669529663687f * LOG2E;  // 32^-0.5 * log2(e)

  const long bhbase = (long)bh * NTOK * HDIM;
  const float4* kg = (const float4*)(k + bhbase);  // 4096 float4 per (b,h)
  const float4* vg = (const float4*)(v + bhbase);

  // ---- pos-bias MLP: rows 0..42 of the candidate table (log2 domain) ----
  if (tid < NTAB) {
    const float bh_ = -7.0f;
    const float bw_ = (float)(tid / 15) - 7.0f;
    const float bd_ = (float)(tid % 15) - 7.0f;
    float x[12], t[12];
#pragma unroll
    for (int j = 0; j < 12; j++)
      x[j] = bh_ * pw[j] + bw_ * pw[12 + j] + bd_ * pw[24 + j] + pb[j];
    ln_relu12(x, t, g1, b1); mm12(t, x, w1, c1);
    ln_relu12(x, t, g2, b2); mm12(t, x, w2, c2);
    ln_relu12(x, t, g3, b3);
#pragma unroll
    for (int hd = 0; hd < NHEADS; hd++) {
      float acc = c3[hd];
#pragma unroll
      for (int i = 0; i < 12; i++) acc += t[i] * w3[i * NHEADS + hd];
      posb_s[tid * NHEADS + hd] = acc * LOG2E;
    }
  }

  // ---- stage chunk 0 (K rows + V^T) ----
#pragma unroll
  for (int i = 0; i < 2; i++) {
    int f = i * 256 + tid, row = f >> 3, c4 = f & 7;
    float4 e = kg[f];
    h4 eh = { (_Float16)e.x, (_Float16)e.y, (_Float16)e.z, (_Float16)e.w };
    *(h4*)&Ks[0][row * 40 + c4 * 4] = eh;
    float4 w = vg[f];
    Vt[0][(c4 * 4 + 0) * 72 + row] = (_Float16)w.x;
    Vt[0][(c4 * 4 + 1) * 72 + row] = (_Float16)w.y;
    Vt[0][(c4 * 4 + 2) * 72 + row] = (_Float16)w.z;
    Vt[0][(c4 * 4 + 3) * 72 + row] = (_Float16)w.w;
  }
  __syncthreads();

  // reversed-window bias vectors for this head
  if (tid >= 3 && tid < NTAB) {
    f4 pv = { posb_s[tid * NHEADS + h],       posb_s[(tid - 1) * NHEADS + h],
              posb_s[(tid - 2) * NHEADS + h], posb_s[(tid - 3) * NHEADS + h] };
    posw4r[tid] = pv;
  }

  // ---- Q fragments straight from global f32 (pre-scaled, log2 domain) ----
  // q-tiles: qq*8 + wave*2 + {0,1}  (tiles 0..31 per (b,h))
  int qt[2] = { qq * 8 + wave * 2, qq * 8 + wave * 2 + 1 };
  h8 qf[2];
  int qs21[2];
#pragma unroll
  for (int ti = 0; ti < 2; ti++) {
    const float* qrow = q + bhbase + (long)(qt[ti] * 16 + l16) * HDIM + quad * 8;
    float4 a = *(const float4*)qrow;
    float4 b = *(const float4*)(qrow + 4);
    h8 qh = { (_Float16)(a.x * SC), (_Float16)(a.y * SC),
              (_Float16)(a.z * SC), (_Float16)(a.w * SC),
              (_Float16)(b.x * SC), (_Float16)(b.y * SC),
              (_Float16)(b.z * SC), (_Float16)(b.w * SC) };
    qf[ti] = qh;
    qs21[ti] = ds3(qt[ti] * 16) + (l16 >> 3) + (l16 & 7) + 21;
  }
  const int kdq = (quad >> 1) + (quad & 1) * 4;  // quad part of key digit-sum

  f4 o[2][2];
#pragma unroll
  for (int ti = 0; ti < 2; ti++) { o[ti][0] = f4{0,0,0,0}; o[ti][1] = f4{0,0,0,0}; }
  float lp[2] = {0.f, 0.f};

  __syncthreads();   // posw4r ready

#pragma unroll 2
  for (int kc = 0; kc < 8; kc++) {
    const int cur = kc & 1;

    // ---- issue next-chunk loads early (consumed after compute) ----
    float4 kreg0, kreg1, vreg0, vreg1;
    if (kc < 7) {
      const int fb = (kc + 1) * 512 + tid;
      kreg0 = kg[fb];       kreg1 = kg[fb + 256];
      vreg0 = vg[fb];       vreg1 = vg[fb + 256];
    }

    // ---- fragment loads from LDS, shared by both q-tiles ----
    // K: b128, A-frag of 16x16x32 (row=key, k=c). V^T: 8x b64, A-frags of
    // 16x16x16 (row=c', k=key'): vA[hf][t][j] = V[t*16+quad*4+j][hf*16+l16].
    h8 kf[4];
    h4 vA[2][4];
#pragma unroll
    for (int t = 0; t < 4; t++)
      kf[t] = *(const h8*)&Ks[cur][(t * 16 + l16) * 40 + quad * 8];
#pragma unroll
    for (int hf = 0; hf < 2; hf++)
#pragma unroll
      for (int t = 0; t < 4; t++)
        vA[hf][t] = *(const h4*)&Vt[cur][(hf * 16 + l16) * 72 + t * 16 + quad * 4];

#pragma unroll
    for (int ti = 0; ti < 2; ti++) {
      // ---- S^T = K.Q^T + bias (C operand; log2 domain) ----
      f4 s[4];
#pragma unroll
      for (int t = 0; t < 4; t++) {
        int idx0 = qs21[ti] - (kc + t * 2 + kdq);   // in [3,42]
        f4 cin = posw4r[idx0];                      // cin[r] = p[idx0-r]
        s[t] = __builtin_amdgcn_mfma_f32_16x16x32_f16(kf[t], qf[ti], cin, 0, 0, 0);
      }
      // ---- max-free softmax: p = 2^s, packed in-register (no LDS P) ----
      h4 pk[4];
#pragma unroll
      for (int t = 0; t < 4; t++) {
        float p0 = __builtin_amdgcn_exp2f(s[t][0]);
        float p1 = __builtin_amdgcn_exp2f(s[t][1]);
        float p2 = __builtin_amdgcn_exp2f(s[t][2]);
        float p3 = __builtin_amdgcn_exp2f(s[t][3]);
        lp[ti] += (p0 + p1) + (p2 + p3);
        pk[t] = h4{ (_Float16)p0, (_Float16)p1, (_Float16)p2, (_Float16)p3 };
      }
      // ---- O^T += V^T.P over 4 key-blocks of 16; B = pk straight from regs.
      // D layout (col=q=l16, row=c'=quad*4+r) identical to old 16x16x32 PV.
#pragma unroll
      for (int t = 0; t < 4; t++) {
        o[ti][0] = __builtin_amdgcn_mfma_f32_16x16x16f16(vA[0][t], pk[t], o[ti][0], 0, 0, 0);
        o[ti][1] = __builtin_amdgcn_mfma_f32_16x16x16f16(vA[1][t], pk[t], o[ti][1], 0, 0, 0);
      }
    }

    // ---- write next chunk to the other LDS buffer, then one barrier ----
    if (kc < 7) {
      const int nb = cur ^ 1;
#pragma unroll
      for (int i = 0; i < 2; i++) {
        float4 e = (i == 0) ? kreg0 : kreg1;
        float4 w = (i == 0) ? vreg0 : vreg1;
        int f = i * 256 + tid, row = f >> 3, c4 = f & 7;
        h4 eh = { (_Float16)e.x, (_Float16)e.y, (_Float16)e.z, (_Float16)e.w };
        *(h4*)&Ks[nb][row * 40 + c4 * 4] = eh;
        Vt[nb][(c4 * 4 + 0) * 72 + row] = (_Float16)w.x;
        Vt[nb][(c4 * 4 + 1) * 72 + row] = (_Float16)w.y;
        Vt[nb][(c4 * 4 + 2) * 72 + row] = (_Float16)w.z;
        Vt[nb][(c4 * 4 + 3) * 72 + row] = (_Float16)w.w;
      }
      __syncthreads();
    }
  }

  // ---- epilogue: reduce l across quads, normalize, LDS transpose, store ----
#pragma unroll
  for (int ti = 0; ti < 2; ti++) {
    float l = lp[ti];
    l += __shfl_xor(l, 16);
    l += __shfl_xor(l, 32);
    const float inv = 1.f / l;      // full row sum for query col l16
    float* os = (float*)smem[wave][ti];
    f4 w0 = { o[ti][0][0] * inv, o[ti][0][1] * inv, o[ti][0][2] * inv, o[ti][0][3] * inv };
    f4 w1 = { o[ti][1][0] * inv, o[ti][1][1] * inv, o[ti][1][2] * inv, o[ti][1][3] * inv };
    *(f4*)&os[l16 * 36 + quad * 4]      = w0;   // Os[q][c], c = quad*4..+3
    *(f4*)&os[l16 * 36 + 16 + quad * 4] = w1;   // c = 16+quad*4..+3
    const int q_ = lane >> 2, seg = lane & 3;
    f4 r0 = *(const f4*)&os[q_ * 36 + seg * 8];
    f4 r1 = *(const f4*)&os[q_ * 36 + seg * 8 + 4];
    float* orow = out + (long)bh * NTOK * HDIM + (long)(qt[ti] * 16 + q_) * HDIM + seg * 8;
    *(float4*)orow       = *(float4*)&r0;   // fully coalesced 2 KB/wave
    *(float4*)(orow + 4) = *(float4*)&r1;
  }
}

extern "C" void kernel_launch(void* const* d_in, const int* in_sizes, int n_in,
                              void* d_out, int out_size, void* d_ws, size_t ws_size,
                              hipStream_t stream) {
  (void)in_sizes; (void)n_in; (void)out_size; (void)d_ws; (void)ws_size;
  const float* q  = (const float*)d_in[0];
  const float* k  = (const float*)d_in[1];
  const float* v  = (const float*)d_in[2];
  // d_in[3..5] = h,w,d scalars (always 8; hard-coded)
  const float* pw  = (const float*)d_in[6];
  const float* pb  = (const float*)d_in[7];
  const float* g1  = (const float*)d_in[8];
  const float* b1  = (const float*)d_in[9];
  const float* w1  = (const float*)d_in[10];
  const float* c1  = (const float*)d_in[11];
  const float* g2  = (const float*)d_in[12];
  const float* b2  = (const float*)d_in[13];
  const float* w2  = (const float*)d_in[14];
  const float* c2  = (const float*)d_in[15];
  const float* g3  = (const float*)d_in[16];
  const float* b3  = (const float*)d_in[17];
  const float* w3  = (const float*)d_in[18];
  const float* c3  = (const float*)d_in[19];
  float* outp = (float*)d_out;

  fused_attn_kernel<<<dim3(384, 4), 256, 0, stream>>>(
      q, k, v,
      pw, pb, g1, b1, w1, c1, g2, b2, w2, c2, g3, b3, w3, c3, outp);
}